// Round 24
// baseline (294.991 us; speedup 1.0000x reference)
//
#include <hip/hip_runtime.h>
#include <hip/hip_bf16.h>
#include <cstddef>

typedef _Float16 h2 __attribute__((ext_vector_type(2)));
typedef _Float16 half8 __attribute__((ext_vector_type(8)));
typedef float f32x4 __attribute__((ext_vector_type(4)));
typedef __fp16 fp16x2 __attribute__((ext_vector_type(2)));

// tanh via exp + hardware rcp (1-ulp): 1 - 2*rcp(e^{2x}+1).
__device__ __forceinline__ float fast_tanh(float x) {
    float e = __expf(2.0f * x);
    return 1.0f - 2.0f * __builtin_amdgcn_rcpf(e + 1.0f);
}
__device__ __forceinline__ unsigned int pkrtz(float a, float b) {
    fp16x2 r = __builtin_amdgcn_cvt_pkrtz(a, b);
    union { fp16x2 h; unsigned int u; } v; v.h = r; return v.u;
}
__device__ __forceinline__ unsigned int pkh(float a, float b) {
    union { _Float16 h; unsigned short u; } x, y;
    x.h = (_Float16)a; y.h = (_Float16)b;
    return ((unsigned int)y.u << 16) | (unsigned int)x.u;
}
__device__ __forceinline__ unsigned short f2h(float a) {
    union { _Float16 h; unsigned short u; } x;
    x.h = (_Float16)a; return x.u;
}
__device__ __forceinline__ float fdot2u(unsigned int a, unsigned int b, float c) {
    union U { unsigned int u; h2 h; };
    U ua; ua.u = a;
    U ub; ub.u = b;
    return __builtin_amdgcn_fdot2(ua.h, ub.h, c, false);
}

// conv0 staging slot tables (round-7 HW-verified): p = 4*h + d.
#define TY64 0x11B44891A440ULL      // 3 bits per p
#define TX64 0xF120120120120120ULL  // 4 bits per p, value = tx/2
#define XST 38                      // staging row stride in dwords
#define S1SZ 8448                   // s1: 32x32 pix x 8 dw (+ slack)
#define IMGS 4

__device__ __forceinline__ void slotf(int p, int& ty, int& tx) {
    ty = (int)((TY64 >> (3 * p)) & 7);
    tx = (int)((TX64 >> (4 * p)) & 15) * 2;
}

// ---------------------------------------------------------------------------
// pack (r22 verbatim): w0mf + c3pk + w1a (t = 2s+tp map) + c5pk/l1pk
__global__ void pack_weights(const float* __restrict__ c1_w,
                             const float* __restrict__ filters,
                             const float* __restrict__ c3_w,
                             const float* __restrict__ c5_w,
                             const float* __restrict__ l1_w,
                             unsigned int* __restrict__ w0mf,
                             unsigned int* __restrict__ c3pk,
                             unsigned int* __restrict__ w1a,
                             unsigned int* __restrict__ c5pk,
                             unsigned int* __restrict__ l1pk) {
    int t = blockIdx.x * blockDim.x + threadIdx.x;
    if (t < 256) {
        int d = t & 3, oc = (t >> 2) & 15, hh = (t >> 6) & 3;
        int p = 4 * hh + d, ty, tx; slotf(p, ty, tx);
        float lo = 0.f, hi = 0.f;
        if (p != 15) {
            const float* w = filters + oc * 25 + ty * 5 + tx;
            lo = w[0]; hi = (tx < 4) ? w[1] : 0.f;
        }
        w0mf[t] = pkh(lo, hi);
    } else if (t >= 4352 && t < 4352 + 480) {
        int g = t - 4352;
        int oc = g / 30, rem = g % 30, ic = rem / 5, ky = rem % 5;
        const float* w = c3_w + (oc * 6 + ic) * 25 + ky * 5;
        unsigned int* d = c3pk + (oc * 6 + ic) * 32 + ky * 6;
        d[0] = pkh(w[0], w[1]); d[1] = pkh(w[2], w[3]); d[2] = pkh(w[4], 0.f);
        d[3] = pkh(0.f, w[0]); d[4] = pkh(w[1], w[2]); d[5] = pkh(w[3], w[4]);
        if (ky == 0) {
            unsigned int* p2 = c3pk + (oc * 6 + ic) * 32;
            p2[30] = 0u; p2[31] = 0u;
        }
    } else if (t >= 4864 && t < 4864 + 3840) {
        int g = t - 4864;                 // = s*256 + lane*4 + d
        int s = g >> 8;
        int rem = g & 255;
        int lane = rem >> 2, d = rem & 3;
        int h = lane >> 4, cc = lane & 15;
        int tt = 2 * s + (h >> 1);        // 0..29 (r22 map)
        int jy = tt / 5, kx = tt % 5;
        int icA = 8 * (h & 1) + 2 * d;
        float lo = 0.f, hi = 0.f;
        if (cc < 12) {
            int oc = cc >> 1, ry = cc & 1;
            int ky = jy - ry;
            if (ky >= 0 && ky <= 4) {
                lo = c1_w[(oc * 16 + icA) * 25 + ky * 5 + kx];
                hi = c1_w[(oc * 16 + icA + 1) * 25 + ky * 5 + kx];
            }
        }
        w1a[g] = pkh(lo, hi);
    } else if (t >= 8960 && t < 8960 + 24000) {
        int g = t - 8960;
        int o = g / 200, j = g % 200;
        c5pk[o * 200 + j] = pkh(c5_w[o * 400 + 2 * j], c5_w[o * 400 + 2 * j + 1]);
    } else if (t >= 33280 && t < 33280 + 5040) {
        int g = t - 33280;
        int o = g / 60, j = g % 60;
        l1pk[o * 60 + j] = pkh(l1_w[o * 120 + 2 * j], l1_w[o * 120 + 2 * j + 1]);
    }
}

// ---------------------------------------------------------------------------
// Front (r22 verbatim; launch_bounds 8 waves/EU -> 4 blocks/CU target):
// staging -> conv0 MFMA -> paired dword scatter -> conv1 MFMA (oc,ry)-fold.
__global__ __launch_bounds__(512, 8) void lenet_front(
    const float* __restrict__ x,
    const unsigned int* __restrict__ w0mf,
    const unsigned int* __restrict__ w1a,
    const float* __restrict__ c1_b,
    float* __restrict__ out2)
{
    __shared__ __align__(16) unsigned int s1[S1SZ];

    const int b = blockIdx.x;
    const int tid = threadIdx.x;
    const int lane = tid & 63;
    const int wid = tid >> 6;
    const int h = (lane >> 4) & 3;
    const int c = lane & 15;
    const float* xb = x + (size_t)b * 1024;

    for (int i = tid; i < 1368; i += 512) s1[i] = 0u;
    if (tid < 256) s1[8192 + tid] = 0u;

    int offd[4];
#pragma unroll
    for (int d = 0; d < 4; ++d) {
        int p = 4 * h + d, ty, tx; slotf(p, ty, tx);
        offd[d] = ty * XST + tx + c;
    }
    half8 af0 = *(const half8*)(w0mf + (h * 16 + c) * 4);

    half8 afc[15];
#pragma unroll
    for (int s = 0; s < 15; s++)
        afc[s] = *(const half8*)(w1a + (s * 64 + lane) * 4);
    __syncthreads();

    // P0: input -> pair-dup f16 staging rows
    {
        int r = tid >> 4, cc = tid & 15;
        float2 v = *(const float2*)(xb + r * 32 + cc * 2);
        float vnext = __shfl(v.x, lane + 1);
        if (cc == 15) vnext = 0.f;
        unsigned int d0 = pkrtz(v.x, v.y);
        unsigned int d1 = pkrtz(v.y, vnext);
        unsigned int* row = &s1[(r + 2) * XST];
        *(uint2*)&row[2 * cc + 2] = make_uint2(d0, d1);
        if (cc == 0) row[1] = pkrtz(0.f, v.x);
    }
    __syncthreads();

    union H8 { unsigned int u[4]; half8 hv; };
    union U4H { uint4 u; half8 hv; };

    // P1a: conv0 MFMA into regs
    f32x4 AC0[4], AC1[4];
#pragma unroll
    for (int yi = 0; yi < 4; ++yi) {
        const int y = 4 * wid + yi;
        const int base = y * XST;
        H8 B0, B1;
#pragma unroll
        for (int d = 0; d < 4; ++d) {
            B0.u[d] = s1[base + offd[d]];
            B1.u[d] = s1[base + 16 + offd[d]];
        }
        f32x4 z = {0.f, 0.f, 0.f, 0.f};
        AC0[yi] = __builtin_amdgcn_mfma_f32_16x16x32_f16(af0, B0.hv, z, 0, 0, 0);
        AC1[yi] = __builtin_amdgcn_mfma_f32_16x16x32_f16(af0, B1.hv, z, 0, 0, 0);
    }
    __syncthreads();

    // P1b: tanh + paired dword stores
    {
#pragma unroll
        for (int yi = 0; yi < 4; ++yi) {
            const int y = 4 * wid + yi;
            const int ybase = y * 256;
#pragma unroll
            for (int pr = 0; pr < 2; ++pr) {
                unsigned int w0 = pkh(fast_tanh(AC0[yi][2 * pr]),
                                      fast_tanh(AC0[yi][2 * pr + 1]));
                unsigned int w1 = pkh(fast_tanh(AC1[yi][2 * pr]),
                                      fast_tanh(AC1[yi][2 * pr + 1]));
                int dwA = (ybase + c * 8 + 2 * h + pr) ^ (c & 12);
                s1[dwA] = w0;
                s1[dwA + 128] = w1;
            }
        }
    }
    __syncthreads();

    // P2: conv1 MFMA, (oc,ry)-folded M, 15 K-steps (r22 addressing)
    const bool hi2 = (h >= 2);
    const int ih4 = 4 * (h & 1);

    const float bj0 = c1_b[h < 3 ? 2 * h : 0];
    const float bj1 = c1_b[h < 3 ? 2 * h + 1 : 0];

#pragma unroll 1
    for (int q = wid; q < 28; q += 8) {
        const int py = q >> 1;
        const int xh = q & 1;
        const int x0 = 12 * xh;
        const int yy = 2 * py;
        const int xc = x0 + c;
        const int bk = yy * 256 + xc * 8 + ih4;

        f32x4 accE = {0.f, 0.f, 0.f, 0.f};
        f32x4 accO = {0.f, 0.f, 0.f, 0.f};
        __builtin_amdgcn_s_setprio(1);
#pragma unroll
        for (int s = 0; s < 15; s++) {
            const int t0 = 2 * s, t1 = 2 * s + 1;
            const int K0 = (t0 / 5) * 256 + (t0 % 5) * 8;
            const int K1 = (t1 / 5) * 256 + (t1 % 5) * 8;
            const int X0 = t0 % 5, X1 = t1 % 5;
            int Ks = hi2 ? K1 : K0;
            int txs = hi2 ? X1 : X0;
            int x2 = xc + txs;
            int dw = (bk + Ks) ^ (x2 & 12);
            U4H B;
            B.u = *(const uint4*)&s1[dw];
            if (s & 1) accO = __builtin_amdgcn_mfma_f32_16x16x32_f16(afc[s], B.hv, accO, 0, 0, 0);
            else       accE = __builtin_amdgcn_mfma_f32_16x16x32_f16(afc[s], B.hv, accE, 0, 0, 0);
        }
        __builtin_amdgcn_s_setprio(0);
        f32x4 acc = accE + accO;

        float sA = fast_tanh(acc[0] + bj0) + fast_tanh(acc[1] + bj0);
        float sB = fast_tanh(acc[2] + bj1) + fast_tanh(acc[3] + bj1);
        sA += __shfl_xor(sA, 1);
        sB += __shfl_xor(sB, 1);
        int pq = (c >> 1) + 6 * xh;
        bool ok = (h < 3) && ((c & 1) == 0) && (xh ? (pq >= 7) : (pq <= 6));
        if (ok) {
            out2[((size_t)b * 6 + 2 * h) * 196 + py * 14 + pq]     = 0.25f * sA;
            out2[((size_t)b * 6 + 2 * h + 1) * 196 + py * 14 + pq] = 0.25f * sB;
        }
    }
}

// ---------------------------------------------------------------------------
// Back (r22 verbatim, IMGS=4): a2 f32->f16; conv3 dot2 -> c5 f16 -> fc1 f16
// -> fc2 f32.
__global__ __launch_bounds__(256) void lenet_back(
    const float* __restrict__ out2,
    const unsigned int* __restrict__ c3pk, const float* __restrict__ c3_b,
    const unsigned int* __restrict__ c5pk, const float* __restrict__ c5_b,
    const unsigned int* __restrict__ l1pk, const float* __restrict__ l1_b,
    const float* __restrict__ l2_w, const float* __restrict__ l2_b,
    float* __restrict__ out, int B)
{
    __shared__ unsigned int a2f[IMGS][84 * 9];
    __shared__ __align__(16) unsigned short a3h[IMGS][400];
    __shared__ __align__(16) unsigned short f5h[IMGS][120];
    __shared__ float f6[IMGS][84];

    const int b0 = blockIdx.x * IMGS;
    const int tid = threadIdx.x;

    for (int i = tid; i < 588 * IMGS; i += 256) {
        int img = i / 588, rem = i % 588;
        int r = rem / 7, j = rem % 7;
        unsigned int pv = 0u;
        if (b0 + img < B) {
            const float2 v = *(const float2*)(out2 + (size_t)(b0 + img) * 1176 + r * 14 + 2 * j);
            pv = pkh(v.x, v.y);
        }
        a2f[img][r * 9 + j] = pv;
    }
    __syncthreads();

    for (int t = tid; t < 400; t += 256) {
        const int oc = t / 25;
        const int rr = t % 25;
        const int py = rr / 5, px = rr % 5;
        const int y0 = py * 2;
        float a00[IMGS], a01[IMGS], a10[IMGS], a11[IMGS];
#pragma unroll
        for (int g = 0; g < IMGS; g++) { a00[g] = 0.f; a01[g] = 0.f; a10[g] = 0.f; a11[g] = 0.f; }
#pragma unroll 1
        for (int ic = 0; ic < 6; ic++) {
            unsigned int wu[32];
            const uint4* wb = (const uint4*)(c3pk + (oc * 6 + ic) * 32);
#pragma unroll
            for (int qv = 0; qv < 8; qv++) {
                uint4 v = wb[qv];
                wu[4 * qv + 0] = v.x; wu[4 * qv + 1] = v.y;
                wu[4 * qv + 2] = v.z; wu[4 * qv + 3] = v.w;
            }
#pragma unroll
            for (int t6 = 0; t6 < 6; t6++) {
                const int rowoff = (ic * 14 + y0 + t6) * 9 + px;
#pragma unroll
                for (int g = 0; g < IMGS; g++) {
                    const unsigned int* sp = &a2f[g][rowoff];
                    unsigned int s0 = sp[0], s1v = sp[1], s2 = sp[2];
                    if (t6 < 5) {
                        const int kb = t6 * 6;
                        a00[g] = fdot2u(wu[kb + 0], s0, a00[g]);
                        a00[g] = fdot2u(wu[kb + 1], s1v, a00[g]);
                        a00[g] = fdot2u(wu[kb + 2], s2, a00[g]);
                        a01[g] = fdot2u(wu[kb + 3], s0, a01[g]);
                        a01[g] = fdot2u(wu[kb + 4], s1v, a01[g]);
                        a01[g] = fdot2u(wu[kb + 5], s2, a01[g]);
                    }
                    if (t6 >= 1) {
                        const int kb = (t6 - 1) * 6;
                        a10[g] = fdot2u(wu[kb + 0], s0, a10[g]);
                        a10[g] = fdot2u(wu[kb + 1], s1v, a10[g]);
                        a10[g] = fdot2u(wu[kb + 2], s2, a10[g]);
                        a11[g] = fdot2u(wu[kb + 3], s0, a11[g]);
                        a11[g] = fdot2u(wu[kb + 4], s1v, a11[g]);
                        a11[g] = fdot2u(wu[kb + 5], s2, a11[g]);
                    }
                }
            }
        }
        const float bb = c3_b[oc];
#pragma unroll
        for (int g = 0; g < IMGS; g++) {
            a3h[g][t] = f2h(0.25f * (fast_tanh(a00[g] + bb) + fast_tanh(a01[g] + bb) +
                                     fast_tanh(a10[g] + bb) + fast_tanh(a11[g] + bb)));
        }
    }
    __syncthreads();

    if (tid < 240) {
        const int o = tid >> 1;
        const int part = tid & 1;
        float acc[IMGS] = {0.f, 0.f, 0.f, 0.f};
        const uint4* wp = (const uint4*)(c5pk + o * 200 + part * 100);
#pragma unroll 5
        for (int qv = 0; qv < 25; qv++) {
            uint4 wv = wp[qv];
#pragma unroll
            for (int g = 0; g < IMGS; g++) {
                uint4 av = ((const uint4*)a3h[g])[part * 25 + qv];
                acc[g] = fdot2u(wv.x, av.x, acc[g]);
                acc[g] = fdot2u(wv.y, av.y, acc[g]);
                acc[g] = fdot2u(wv.z, av.z, acc[g]);
                acc[g] = fdot2u(wv.w, av.w, acc[g]);
            }
        }
#pragma unroll
        for (int g = 0; g < IMGS; g++) {
            acc[g] += __shfl_xor(acc[g], 1);
            if (part == 0) f5h[g][o] = f2h(fast_tanh(acc[g] + c5_b[o]));
        }
    }
    __syncthreads();

    if (tid < 84) {
        float acc[IMGS];
        const float bb = l1_b[tid];
#pragma unroll
        for (int g = 0; g < IMGS; g++) acc[g] = bb;
        const uint4* wp = (const uint4*)(l1pk + tid * 60);
#pragma unroll 5
        for (int qv = 0; qv < 15; qv++) {
            uint4 wv = wp[qv];
#pragma unroll
            for (int g = 0; g < IMGS; g++) {
                uint4 fv = ((const uint4*)f5h[g])[qv];
                acc[g] = fdot2u(wv.x, fv.x, acc[g]);
                acc[g] = fdot2u(wv.y, fv.y, acc[g]);
                acc[g] = fdot2u(wv.z, fv.z, acc[g]);
                acc[g] = fdot2u(wv.w, fv.w, acc[g]);
            }
        }
#pragma unroll
        for (int g = 0; g < IMGS; g++) f6[g][tid] = fast_tanh(acc[g]);
    }
    __syncthreads();

    if (tid < 10) {
        float acc[IMGS];
        const float bb = l2_b[tid];
#pragma unroll
        for (int g = 0; g < IMGS; g++) acc[g] = bb;
        const float* wp = l2_w + tid * 84;
#pragma unroll 4
        for (int qv = 0; qv < 84; qv++) {
            float w = wp[qv];
#pragma unroll
            for (int g = 0; g < IMGS; g++) acc[g] += w * f6[g][qv];
        }
#pragma unroll
        for (int g = 0; g < IMGS; g++)
            if (b0 + g < B) out[(size_t)(b0 + g) * 10 + tid] = acc[g];
    }
}

extern "C" void kernel_launch(void* const* d_in, const int* in_sizes, int n_in,
                              void* d_out, int out_size, void* d_ws, size_t ws_size,
                              hipStream_t stream) {
    const float* x       = (const float*)d_in[0];
    const float* filters = (const float*)d_in[1];
    const float* c1_w    = (const float*)d_in[2];
    const float* c1_b    = (const float*)d_in[3];
    const float* c3_w    = (const float*)d_in[4];
    const float* c3_b    = (const float*)d_in[5];
    const float* c5_w    = (const float*)d_in[6];
    const float* c5_b    = (const float*)d_in[7];
    const float* l1_w    = (const float*)d_in[8];
    const float* l1_b    = (const float*)d_in[9];
    const float* l2_w    = (const float*)d_in[10];
    const float* l2_b    = (const float*)d_in[11];
    float* out = (float*)d_out;

    const int B = in_sizes[0] / 1024;

    // ws: [w0mf @0][c3pk @17408][w1a @29696 (15360B)][c5pk @46080 (96000B)]
    //     [l1pk @142336 (20160B)][out2 @163840]
    unsigned int* w0mf = (unsigned int*)d_ws;
    unsigned int* c3pk = (unsigned int*)((char*)d_ws + 17408);
    unsigned int* w1a  = (unsigned int*)((char*)d_ws + 29696);
    unsigned int* c5pk = (unsigned int*)((char*)d_ws + 46080);
    unsigned int* l1pk = (unsigned int*)((char*)d_ws + 142336);
    float* out2 = (float*)((char*)d_ws + 163840);

    pack_weights<<<150, 256, 0, stream>>>(c1_w, filters, c3_w, c5_w, l1_w,
                                          w0mf, c3pk, w1a, c5pk, l1pk);
    lenet_front<<<B, 512, 0, stream>>>(x, w0mf, w1a, c1_b, out2);
    lenet_back<<<(B + IMGS - 1) / IMGS, 256, 0, stream>>>(
        out2, c3pk, c3_b, c5pk, c5_b, l1pk, l1_b, l2_w, l2_b, out, B);
}

// Round 25
// 113.457 us; speedup vs baseline: 2.6000x; 2.6000x over previous
//
#include <hip/hip_runtime.h>
#include <hip/hip_bf16.h>
#include <cstddef>

typedef _Float16 h2 __attribute__((ext_vector_type(2)));
typedef _Float16 half8 __attribute__((ext_vector_type(8)));
typedef float f32x4 __attribute__((ext_vector_type(4)));
typedef __fp16 fp16x2 __attribute__((ext_vector_type(2)));

// tanh via exp + hardware rcp (1-ulp): 1 - 2*rcp(e^{2x}+1).
__device__ __forceinline__ float fast_tanh(float x) {
    float e = __expf(2.0f * x);
    return 1.0f - 2.0f * __builtin_amdgcn_rcpf(e + 1.0f);
}
__device__ __forceinline__ unsigned int pkrtz(float a, float b) {
    fp16x2 r = __builtin_amdgcn_cvt_pkrtz(a, b);
    union { fp16x2 h; unsigned int u; } v; v.h = r; return v.u;
}
__device__ __forceinline__ unsigned int pkh(float a, float b) {
    union { _Float16 h; unsigned short u; } x, y;
    x.h = (_Float16)a; y.h = (_Float16)b;
    return ((unsigned int)y.u << 16) | (unsigned int)x.u;
}
__device__ __forceinline__ unsigned short f2h(float a) {
    union { _Float16 h; unsigned short u; } x;
    x.h = (_Float16)a; return x.u;
}
__device__ __forceinline__ float fdot2u(unsigned int a, unsigned int b, float c) {
    union U { unsigned int u; h2 h; };
    U ua; ua.u = a;
    U ub; ub.u = b;
    return __builtin_amdgcn_fdot2(ua.h, ub.h, c, false);
}

// conv0 staging slot tables (round-7 HW-verified): p = 4*h + d.
#define TY64 0x11B44891A440ULL      // 3 bits per p
#define TX64 0xF120120120120120ULL  // 4 bits per p, value = tx/2
#define XST 38                      // staging row stride in dwords
#define S1SZ 8448                   // s1: 32x32 pix x 8 dw (+ slack)
#define IMGS 4

__device__ __forceinline__ void slotf(int p, int& ty, int& tx) {
    ty = (int)((TY64 >> (3 * p)) & 7);
    tx = (int)((TX64 >> (4 * p)) & 15) * 2;
}

// ---------------------------------------------------------------------------
// pack (r22 verbatim): w0mf + c3pk + w1a (t = 2s+tp map) + c5pk/l1pk
__global__ void pack_weights(const float* __restrict__ c1_w,
                             const float* __restrict__ filters,
                             const float* __restrict__ c3_w,
                             const float* __restrict__ c5_w,
                             const float* __restrict__ l1_w,
                             unsigned int* __restrict__ w0mf,
                             unsigned int* __restrict__ c3pk,
                             unsigned int* __restrict__ w1a,
                             unsigned int* __restrict__ c5pk,
                             unsigned int* __restrict__ l1pk) {
    int t = blockIdx.x * blockDim.x + threadIdx.x;
    if (t < 256) {
        int d = t & 3, oc = (t >> 2) & 15, hh = (t >> 6) & 3;
        int p = 4 * hh + d, ty, tx; slotf(p, ty, tx);
        float lo = 0.f, hi = 0.f;
        if (p != 15) {
            const float* w = filters + oc * 25 + ty * 5 + tx;
            lo = w[0]; hi = (tx < 4) ? w[1] : 0.f;
        }
        w0mf[t] = pkh(lo, hi);
    } else if (t >= 4352 && t < 4352 + 480) {
        int g = t - 4352;
        int oc = g / 30, rem = g % 30, ic = rem / 5, ky = rem % 5;
        const float* w = c3_w + (oc * 6 + ic) * 25 + ky * 5;
        unsigned int* d = c3pk + (oc * 6 + ic) * 32 + ky * 6;
        d[0] = pkh(w[0], w[1]); d[1] = pkh(w[2], w[3]); d[2] = pkh(w[4], 0.f);
        d[3] = pkh(0.f, w[0]); d[4] = pkh(w[1], w[2]); d[5] = pkh(w[3], w[4]);
        if (ky == 0) {
            unsigned int* p2 = c3pk + (oc * 6 + ic) * 32;
            p2[30] = 0u; p2[31] = 0u;
        }
    } else if (t >= 4864 && t < 4864 + 3840) {
        int g = t - 4864;                 // = s*256 + lane*4 + d
        int s = g >> 8;
        int rem = g & 255;
        int lane = rem >> 2, d = rem & 3;
        int h = lane >> 4, cc = lane & 15;
        int tt = 2 * s + (h >> 1);        // 0..29 (r22 map)
        int jy = tt / 5, kx = tt % 5;
        int icA = 8 * (h & 1) + 2 * d;
        float lo = 0.f, hi = 0.f;
        if (cc < 12) {
            int oc = cc >> 1, ry = cc & 1;
            int ky = jy - ry;
            if (ky >= 0 && ky <= 4) {
                lo = c1_w[(oc * 16 + icA) * 25 + ky * 5 + kx];
                hi = c1_w[(oc * 16 + icA + 1) * 25 + ky * 5 + kx];
            }
        }
        w1a[g] = pkh(lo, hi);
    } else if (t >= 8960 && t < 8960 + 24000) {
        int g = t - 8960;
        int o = g / 200, j = g % 200;
        c5pk[o * 200 + j] = pkh(c5_w[o * 400 + 2 * j], c5_w[o * 400 + 2 * j + 1]);
    } else if (t >= 33280 && t < 33280 + 5040) {
        int g = t - 33280;
        int o = g / 60, j = g % 60;
        l1pk[o * 60 + j] = pkh(l1_w[o * 120 + 2 * j], l1_w[o * 120 + 2 * j + 1]);
    }
}

// ---------------------------------------------------------------------------
// Front (r22 verbatim, launch_bounds(512,2)): staging -> conv0 MFMA ->
// paired dword scatter -> conv1 MFMA (oc,ry)-fold, 15 K-steps.
__global__ __launch_bounds__(512, 2) void lenet_front(
    const float* __restrict__ x,
    const unsigned int* __restrict__ w0mf,
    const unsigned int* __restrict__ w1a,
    const float* __restrict__ c1_b,
    float* __restrict__ out2)
{
    __shared__ __align__(16) unsigned int s1[S1SZ];

    const int b = blockIdx.x;
    const int tid = threadIdx.x;
    const int lane = tid & 63;
    const int wid = tid >> 6;
    const int h = (lane >> 4) & 3;
    const int c = lane & 15;
    const float* xb = x + (size_t)b * 1024;

    for (int i = tid; i < 1368; i += 512) s1[i] = 0u;
    if (tid < 256) s1[8192 + tid] = 0u;

    int offd[4];
#pragma unroll
    for (int d = 0; d < 4; ++d) {
        int p = 4 * h + d, ty, tx; slotf(p, ty, tx);
        offd[d] = ty * XST + tx + c;
    }
    half8 af0 = *(const half8*)(w0mf + (h * 16 + c) * 4);

    half8 afc[15];
#pragma unroll
    for (int s = 0; s < 15; s++)
        afc[s] = *(const half8*)(w1a + (s * 64 + lane) * 4);
    __syncthreads();

    // P0: input -> pair-dup f16 staging rows
    {
        int r = tid >> 4, cc = tid & 15;
        float2 v = *(const float2*)(xb + r * 32 + cc * 2);
        float vnext = __shfl(v.x, lane + 1);
        if (cc == 15) vnext = 0.f;
        unsigned int d0 = pkrtz(v.x, v.y);
        unsigned int d1 = pkrtz(v.y, vnext);
        unsigned int* row = &s1[(r + 2) * XST];
        *(uint2*)&row[2 * cc + 2] = make_uint2(d0, d1);
        if (cc == 0) row[1] = pkrtz(0.f, v.x);
    }
    __syncthreads();

    union H8 { unsigned int u[4]; half8 hv; };
    union U4H { uint4 u; half8 hv; };

    // P1a: conv0 MFMA into regs
    f32x4 AC0[4], AC1[4];
#pragma unroll
    for (int yi = 0; yi < 4; ++yi) {
        const int y = 4 * wid + yi;
        const int base = y * XST;
        H8 B0, B1;
#pragma unroll
        for (int d = 0; d < 4; ++d) {
            B0.u[d] = s1[base + offd[d]];
            B1.u[d] = s1[base + 16 + offd[d]];
        }
        f32x4 z = {0.f, 0.f, 0.f, 0.f};
        AC0[yi] = __builtin_amdgcn_mfma_f32_16x16x32_f16(af0, B0.hv, z, 0, 0, 0);
        AC1[yi] = __builtin_amdgcn_mfma_f32_16x16x32_f16(af0, B1.hv, z, 0, 0, 0);
    }
    __syncthreads();

    // P1b: tanh + paired dword stores
    {
#pragma unroll
        for (int yi = 0; yi < 4; ++yi) {
            const int y = 4 * wid + yi;
            const int ybase = y * 256;
#pragma unroll
            for (int pr = 0; pr < 2; ++pr) {
                unsigned int w0 = pkh(fast_tanh(AC0[yi][2 * pr]),
                                      fast_tanh(AC0[yi][2 * pr + 1]));
                unsigned int w1 = pkh(fast_tanh(AC1[yi][2 * pr]),
                                      fast_tanh(AC1[yi][2 * pr + 1]));
                int dwA = (ybase + c * 8 + 2 * h + pr) ^ (c & 12);
                s1[dwA] = w0;
                s1[dwA + 128] = w1;
            }
        }
    }
    __syncthreads();

    // P2: conv1 MFMA, (oc,ry)-folded M, 15 K-steps (r22 addressing)
    const bool hi2 = (h >= 2);
    const int ih4 = 4 * (h & 1);

    const float bj0 = c1_b[h < 3 ? 2 * h : 0];
    const float bj1 = c1_b[h < 3 ? 2 * h + 1 : 0];

#pragma unroll 1
    for (int q = wid; q < 28; q += 8) {
        const int py = q >> 1;
        const int xh = q & 1;
        const int x0 = 12 * xh;
        const int yy = 2 * py;
        const int xc = x0 + c;
        const int bk = yy * 256 + xc * 8 + ih4;

        f32x4 accE = {0.f, 0.f, 0.f, 0.f};
        f32x4 accO = {0.f, 0.f, 0.f, 0.f};
        __builtin_amdgcn_s_setprio(1);
#pragma unroll
        for (int s = 0; s < 15; s++) {
            const int t0 = 2 * s, t1 = 2 * s + 1;
            const int K0 = (t0 / 5) * 256 + (t0 % 5) * 8;
            const int K1 = (t1 / 5) * 256 + (t1 % 5) * 8;
            const int X0 = t0 % 5, X1 = t1 % 5;
            int Ks = hi2 ? K1 : K0;
            int txs = hi2 ? X1 : X0;
            int x2 = xc + txs;
            int dw = (bk + Ks) ^ (x2 & 12);
            U4H B;
            B.u = *(const uint4*)&s1[dw];
            if (s & 1) accO = __builtin_amdgcn_mfma_f32_16x16x32_f16(afc[s], B.hv, accO, 0, 0, 0);
            else       accE = __builtin_amdgcn_mfma_f32_16x16x32_f16(afc[s], B.hv, accE, 0, 0, 0);
        }
        __builtin_amdgcn_s_setprio(0);
        f32x4 acc = accE + accO;

        float sA = fast_tanh(acc[0] + bj0) + fast_tanh(acc[1] + bj0);
        float sB = fast_tanh(acc[2] + bj1) + fast_tanh(acc[3] + bj1);
        sA += __shfl_xor(sA, 1);
        sB += __shfl_xor(sB, 1);
        int pq = (c >> 1) + 6 * xh;
        bool ok = (h < 3) && ((c & 1) == 0) && (xh ? (pq >= 7) : (pq <= 6));
        if (ok) {
            out2[((size_t)b * 6 + 2 * h) * 196 + py * 14 + pq]     = 0.25f * sA;
            out2[((size_t)b * 6 + 2 * h + 1) * 196 + py * 14 + pq] = 0.25f * sB;
        }
    }
}

// ---------------------------------------------------------------------------
// Back (r22 verbatim, IMGS=4): a2 f32->f16; conv3 dot2 -> c5 f16 -> fc1 f16
// -> fc2 f32.
__global__ __launch_bounds__(256) void lenet_back(
    const float* __restrict__ out2,
    const unsigned int* __restrict__ c3pk, const float* __restrict__ c3_b,
    const unsigned int* __restrict__ c5pk, const float* __restrict__ c5_b,
    const unsigned int* __restrict__ l1pk, const float* __restrict__ l1_b,
    const float* __restrict__ l2_w, const float* __restrict__ l2_b,
    float* __restrict__ out, int B)
{
    __shared__ unsigned int a2f[IMGS][84 * 9];
    __shared__ __align__(16) unsigned short a3h[IMGS][400];
    __shared__ __align__(16) unsigned short f5h[IMGS][120];
    __shared__ float f6[IMGS][84];

    const int b0 = blockIdx.x * IMGS;
    const int tid = threadIdx.x;

    for (int i = tid; i < 588 * IMGS; i += 256) {
        int img = i / 588, rem = i % 588;
        int r = rem / 7, j = rem % 7;
        unsigned int pv = 0u;
        if (b0 + img < B) {
            const float2 v = *(const float2*)(out2 + (size_t)(b0 + img) * 1176 + r * 14 + 2 * j);
            pv = pkh(v.x, v.y);
        }
        a2f[img][r * 9 + j] = pv;
    }
    __syncthreads();

    for (int t = tid; t < 400; t += 256) {
        const int oc = t / 25;
        const int rr = t % 25;
        const int py = rr / 5, px = rr % 5;
        const int y0 = py * 2;
        float a00[IMGS], a01[IMGS], a10[IMGS], a11[IMGS];
#pragma unroll
        for (int g = 0; g < IMGS; g++) { a00[g] = 0.f; a01[g] = 0.f; a10[g] = 0.f; a11[g] = 0.f; }
#pragma unroll 1
        for (int ic = 0; ic < 6; ic++) {
            unsigned int wu[32];
            const uint4* wb = (const uint4*)(c3pk + (oc * 6 + ic) * 32);
#pragma unroll
            for (int qv = 0; qv < 8; qv++) {
                uint4 v = wb[qv];
                wu[4 * qv + 0] = v.x; wu[4 * qv + 1] = v.y;
                wu[4 * qv + 2] = v.z; wu[4 * qv + 3] = v.w;
            }
#pragma unroll
            for (int t6 = 0; t6 < 6; t6++) {
                const int rowoff = (ic * 14 + y0 + t6) * 9 + px;
#pragma unroll
                for (int g = 0; g < IMGS; g++) {
                    const unsigned int* sp = &a2f[g][rowoff];
                    unsigned int s0 = sp[0], s1v = sp[1], s2 = sp[2];
                    if (t6 < 5) {
                        const int kb = t6 * 6;
                        a00[g] = fdot2u(wu[kb + 0], s0, a00[g]);
                        a00[g] = fdot2u(wu[kb + 1], s1v, a00[g]);
                        a00[g] = fdot2u(wu[kb + 2], s2, a00[g]);
                        a01[g] = fdot2u(wu[kb + 3], s0, a01[g]);
                        a01[g] = fdot2u(wu[kb + 4], s1v, a01[g]);
                        a01[g] = fdot2u(wu[kb + 5], s2, a01[g]);
                    }
                    if (t6 >= 1) {
                        const int kb = (t6 - 1) * 6;
                        a10[g] = fdot2u(wu[kb + 0], s0, a10[g]);
                        a10[g] = fdot2u(wu[kb + 1], s1v, a10[g]);
                        a10[g] = fdot2u(wu[kb + 2], s2, a10[g]);
                        a11[g] = fdot2u(wu[kb + 3], s0, a11[g]);
                        a11[g] = fdot2u(wu[kb + 4], s1v, a11[g]);
                        a11[g] = fdot2u(wu[kb + 5], s2, a11[g]);
                    }
                }
            }
        }
        const float bb = c3_b[oc];
#pragma unroll
        for (int g = 0; g < IMGS; g++) {
            a3h[g][t] = f2h(0.25f * (fast_tanh(a00[g] + bb) + fast_tanh(a01[g] + bb) +
                                     fast_tanh(a10[g] + bb) + fast_tanh(a11[g] + bb)));
        }
    }
    __syncthreads();

    if (tid < 240) {
        const int o = tid >> 1;
        const int part = tid & 1;
        float acc[IMGS] = {0.f, 0.f, 0.f, 0.f};
        const uint4* wp = (const uint4*)(c5pk + o * 200 + part * 100);
#pragma unroll 5
        for (int qv = 0; qv < 25; qv++) {
            uint4 wv = wp[qv];
#pragma unroll
            for (int g = 0; g < IMGS; g++) {
                uint4 av = ((const uint4*)a3h[g])[part * 25 + qv];
                acc[g] = fdot2u(wv.x, av.x, acc[g]);
                acc[g] = fdot2u(wv.y, av.y, acc[g]);
                acc[g] = fdot2u(wv.z, av.z, acc[g]);
                acc[g] = fdot2u(wv.w, av.w, acc[g]);
            }
        }
#pragma unroll
        for (int g = 0; g < IMGS; g++) {
            acc[g] += __shfl_xor(acc[g], 1);
            if (part == 0) f5h[g][o] = f2h(fast_tanh(acc[g] + c5_b[o]));
        }
    }
    __syncthreads();

    if (tid < 84) {
        float acc[IMGS];
        const float bb = l1_b[tid];
#pragma unroll
        for (int g = 0; g < IMGS; g++) acc[g] = bb;
        const uint4* wp = (const uint4*)(l1pk + tid * 60);
#pragma unroll 5
        for (int qv = 0; qv < 15; qv++) {
            uint4 wv = wp[qv];
#pragma unroll
            for (int g = 0; g < IMGS; g++) {
                uint4 fv = ((const uint4*)f5h[g])[qv];
                acc[g] = fdot2u(wv.x, fv.x, acc[g]);
                acc[g] = fdot2u(wv.y, fv.y, acc[g]);
                acc[g] = fdot2u(wv.z, fv.z, acc[g]);
                acc[g] = fdot2u(wv.w, fv.w, acc[g]);
            }
        }
#pragma unroll
        for (int g = 0; g < IMGS; g++) f6[g][tid] = fast_tanh(acc[g]);
    }
    __syncthreads();

    if (tid < 10) {
        float acc[IMGS];
        const float bb = l2_b[tid];
#pragma unroll
        for (int g = 0; g < IMGS; g++) acc[g] = bb;
        const float* wp = l2_w + tid * 84;
#pragma unroll 4
        for (int qv = 0; qv < 84; qv++) {
            float w = wp[qv];
#pragma unroll
            for (int g = 0; g < IMGS; g++) acc[g] += w * f6[g][qv];
        }
#pragma unroll
        for (int g = 0; g < IMGS; g++)
            if (b0 + g < B) out[(size_t)(b0 + g) * 10 + tid] = acc[g];
    }
}

extern "C" void kernel_launch(void* const* d_in, const int* in_sizes, int n_in,
                              void* d_out, int out_size, void* d_ws, size_t ws_size,
                              hipStream_t stream) {
    const float* x       = (const float*)d_in[0];
    const float* filters = (const float*)d_in[1];
    const float* c1_w    = (const float*)d_in[2];
    const float* c1_b    = (const float*)d_in[3];
    const float* c3_w    = (const float*)d_in[4];
    const float* c3_b    = (const float*)d_in[5];
    const float* c5_w    = (const float*)d_in[6];
    const float* c5_b    = (const float*)d_in[7];
    const float* l1_w    = (const float*)d_in[8];
    const float* l1_b    = (const float*)d_in[9];
    const float* l2_w    = (const float*)d_in[10];
    const float* l2_b    = (const float*)d_in[11];
    float* out = (float*)d_out;

    const int B = in_sizes[0] / 1024;

    // ws: [w0mf @0][c3pk @17408][w1a @29696 (15360B)][c5pk @46080 (96000B)]
    //     [l1pk @142336 (20160B)][out2 @163840]
    unsigned int* w0mf = (unsigned int*)d_ws;
    unsigned int* c3pk = (unsigned int*)((char*)d_ws + 17408);
    unsigned int* w1a  = (unsigned int*)((char*)d_ws + 29696);
    unsigned int* c5pk = (unsigned int*)((char*)d_ws + 46080);
    unsigned int* l1pk = (unsigned int*)((char*)d_ws + 142336);
    float* out2 = (float*)((char*)d_ws + 163840);

    pack_weights<<<150, 256, 0, stream>>>(c1_w, filters, c3_w, c5_w, l1_w,
                                          w0mf, c3pk, w1a, c5pk, l1pk);
    lenet_front<<<B, 512, 0, stream>>>(x, w0mf, w1a, c1_b, out2);
    lenet_back<<<(B + IMGS - 1) / IMGS, 256, 0, stream>>>(
        out2, c3pk, c3_b, c5pk, c5_b, l1pk, l1_b, l2_w, l2_b, out, B);
}